// Round 1
// baseline (235.399 us; speedup 1.0000x reference)
//
#include <hip/hip_runtime.h>
#include <math.h>

// Problem: lkd scan over T=65536 steps, DIM=512, fp32. Closed form:
//   D_t = v + c*t ;  var_t = (v-c) D_t / D_{t-1} ;  mu_t = ((v-c)mu0 + c Z_t)/D_{t-1}
//   Z_t = prefix sum of z over t (per column).
//   lkd = analytic_logdet + Sum_t,d -(z-mu_t)^2 * D_{t-1} / (2 (v-c) D_t)
// Pipeline: K1 chunk colsums -> K2a/K2b 2-level exclusive scan -> K3 main pass.
// Workspace: CHUNKS*DIM + GROUPS*DIM floats = 2MB + 128KB (assumed <= ws_size).
//
// R1 changes vs 233µs baseline: float4 (16B/lane) z loads in K1/K3 (was float2),
// 128-thread blocks with 4 cols/thread; register-prefetch in K2a/K2b scans to
// break the serial load->store->load chain.

#define DIM    512
#define TT     65536
#define CHUNKS 1024
#define ROWS   64      // TT / CHUNKS
#define GROUPS 64
#define CPG    16      // CHUNKS / GROUPS

#define TWO_PI 6.283185307179586

// K1: per-chunk column sums. grid=CHUNKS, block=128 (4 cols/thread, float4 loads).
__global__ __launch_bounds__(128) void k1_colsum(const float* __restrict__ z,
                                                 float* __restrict__ sums) {
    const int chunk = blockIdx.x;
    const int tid = threadIdx.x;  // float4 column index 0..127
    const float4* zp = reinterpret_cast<const float4*>(z)
                       + (size_t)chunk * ROWS * (DIM / 4) + tid;
    float sx = 0.f, sy = 0.f, szs = 0.f, sw = 0.f;
#pragma unroll 16
    for (int r = 0; r < ROWS; ++r) {
        float4 v = zp[(size_t)r * (DIM / 4)];
        sx += v.x; sy += v.y; szs += v.z; sw += v.w;
    }
    reinterpret_cast<float4*>(sums)[(size_t)chunk * (DIM / 4) + tid]
        = make_float4(sx, sy, szs, sw);
}

// K2a: within-group exclusive scan (in place) + group totals. grid=GROUPS, block=512.
// Register-prefetch all CPG values first so loads pipeline.
__global__ __launch_bounds__(512) void k2a_scan(float* __restrict__ sums,
                                                float* __restrict__ gsums) {
    const int g = blockIdx.x;
    const int d = threadIdx.x;
    float vals[CPG];
#pragma unroll
    for (int i = 0; i < CPG; ++i)
        vals[i] = sums[(size_t)(g * CPG + i) * DIM + d];
    float run = 0.f;
#pragma unroll
    for (int i = 0; i < CPG; ++i) {
        sums[(size_t)(g * CPG + i) * DIM + d] = run;
        run += vals[i];
    }
    gsums[(size_t)g * DIM + d] = run;
}

// K2b: exclusive scan over group totals (in place) + analytic log-det term.
__global__ __launch_bounds__(512) void k2b_scan(float* __restrict__ gsums,
                                                const float* __restrict__ var_vbl,
                                                const float* __restrict__ corr_vbl,
                                                float* __restrict__ out) {
    const int d = threadIdx.x;
    float vals[GROUPS];
#pragma unroll
    for (int g = 0; g < GROUPS; ++g)
        vals[g] = gsums[(size_t)g * DIM + d];
    float run = 0.f;
#pragma unroll
    for (int g = 0; g < GROUPS; ++g) {
        gsums[(size_t)g * DIM + d] = run;
        run += vals[g];
    }
    // Analytic: sum_t -0.5*log(2pi var_t) telescopes.
    double sp = log1p(exp((double)var_vbl[d]));
    double v = sp * sp;
    double cc = v / (1.0 + exp(-(double)corr_vbl[d]));
    double vmc = v - cc;
    double Dlast = v + cc * (double)(TT - 1);
    double Ld = -0.5 * ((double)TT * (log(TWO_PI) + log(vmc)) + log(Dlast / vmc));
    __shared__ double red[512];
    red[d] = Ld;
    __syncthreads();
    for (int s = 256; s > 0; s >>= 1) {
        if (d < s) red[d] += red[d + s];
        __syncthreads();
    }
    if (d == 0) atomicAdd(out, (float)red[0]);
}

// K3: main pass — quadratic term. grid=CHUNKS, block=128 (4 cols/thread, float4).
__global__ __launch_bounds__(128) void k3_main(const float* __restrict__ z,
                                               const float* __restrict__ sums,
                                               const float* __restrict__ gsums,
                                               const float* __restrict__ var_vbl,
                                               const float* __restrict__ corr_vbl,
                                               const float* __restrict__ prior_mu,
                                               float* __restrict__ out) {
    const int chunk = blockIdx.x;
    const int tid = threadIdx.x;  // 0..127
    const int d0 = tid * 4;
    const int g = chunk / CPG;
    const float t0m1 = (float)(chunk * ROWS) - 1.0f;

    float vv[4], cc[4], k0[4], kq[4], Z[4], Dprev[4], invDprev[4];
#pragma unroll
    for (int j = 0; j < 4; ++j) {
        const int d = d0 + j;
        float spv = log1pf(expf(var_vbl[d]));
        float v = spv * spv;
        float c = v / (1.0f + expf(-corr_vbl[d]));
        float vmc = v - c;
        vv[j] = v;
        cc[j] = c;
        k0[j] = vmc * prior_mu[d];          // (v-c)*mu0
        kq[j] = 0.5f / vmc;
        Z[j] = sums[(size_t)chunk * DIM + d] + gsums[(size_t)g * DIM + d];
        Dprev[j] = fmaf(c, t0m1, v);        // D_{t0-1}
        invDprev[j] = __builtin_amdgcn_rcpf(Dprev[j]);
    }

    const float4* zp = reinterpret_cast<const float4*>(z)
                       + (size_t)chunk * ROWS * (DIM / 4) + tid;
    float acc = 0.f;
    float tf = t0m1 + 1.0f;
#pragma unroll 4
    for (int r = 0; r < ROWS; ++r) {
        float4 zv = zp[(size_t)r * (DIM / 4)];
        float zz[4] = {zv.x, zv.y, zv.z, zv.w};
#pragma unroll
        for (int j = 0; j < 4; ++j) {
            float Dt = fmaf(cc[j], tf, vv[j]);            // v + c*t
            float invDt = __builtin_amdgcn_rcpf(Dt);
            float mu = fmaf(cc[j], Z[j], k0[j]) * invDprev[j];
            float e = zz[j] - mu;
            acc = fmaf(e * e * Dprev[j] * invDt, kq[j], acc);
            Z[j] += zz[j];
            Dprev[j] = Dt;
            invDprev[j] = invDt;
        }
        tf += 1.0f;
    }

    // block reduce (2 waves) and subtract from out
    for (int off = 32; off > 0; off >>= 1) acc += __shfl_down(acc, off, 64);
    __shared__ float wsred[2];
    const int lane = tid & 63, w = tid >> 6;
    if (lane == 0) wsred[w] = acc;
    __syncthreads();
    if (tid == 0) atomicAdd(out, -(wsred[0] + wsred[1]));
}

extern "C" void kernel_launch(void* const* d_in, const int* in_sizes, int n_in,
                              void* d_out, int out_size, void* d_ws, size_t ws_size,
                              hipStream_t stream) {
    const float* z = (const float*)d_in[0];
    const float* var_vbl = (const float*)d_in[1];
    const float* corr_vbl = (const float*)d_in[2];
    const float* prior_mu = (const float*)d_in[3];
    float* out = (float*)d_out;
    float* sums = (float*)d_ws;                        // CHUNKS*DIM floats (2 MB)
    float* gsums = sums + (size_t)CHUNKS * DIM;        // GROUPS*DIM floats (128 KB)

    hipMemsetAsync(d_out, 0, sizeof(float), stream);
    k1_colsum<<<CHUNKS, 128, 0, stream>>>(z, sums);
    k2a_scan<<<GROUPS, 512, 0, stream>>>(sums, gsums);
    k2b_scan<<<1, 512, 0, stream>>>(gsums, var_vbl, corr_vbl, out);
    k3_main<<<CHUNKS, 128, 0, stream>>>(z, sums, gsums, var_vbl, corr_vbl,
                                        prior_mu, out);
}

// Round 6
// 207.230 us; speedup vs baseline: 1.1359x; 1.1359x over previous
//
#include <hip/hip_runtime.h>
#include <math.h>

// Problem: lkd scan over T=65536 steps, DIM=512, fp32. Closed form:
//   D_t = v + c*t ;  var_t = (v-c) D_t / D_{t-1} ;  mu_t = ((v-c)mu0 + c Z_t)/D_{t-1}
//   Z_t = prefix sum of z over t (per column).
// R2 restructure: single pass over z. Per chunk/column compute moments
//   S0 = sum r_t, S1 = sum r_t w_t, S2 = sum r_t w_t^2,
//   r_t = 1/(D_t D_{t-1}),  w_t = Dprev*z - k0 - c*L_t  (L = local prefix),
// so the quadratic term is kq*(S2 - 2cP*S1 + c^2 P^2*S0) with P = inter-chunk
// prefix. Quadratic pass over z (old K3) is eliminated entirely.
// Pipeline: K1 fused moments -> K2a group sums -> K2b scan+logdet (stores out)
//           -> K2c combine+reduce. No memset (K2b's plain store inits out).
// Workspace: 4*CHUNKS*DIM + GROUPS*DIM floats = 8.125 MB.

#define DIM    512
#define TT     65536
#define CHUNKS 1024
#define ROWS   64      // TT / CHUNKS
#define GROUPS 64
#define CPG    16      // CHUNKS / GROUPS

#define TWO_PI 6.283185307179586

// K1: fused colsum + moment pass. grid=CHUNKS, block=128 (4 cols/thread, float4).
__global__ __launch_bounds__(128) void k1_fused(const float* __restrict__ z,
                                                const float* __restrict__ var_vbl,
                                                const float* __restrict__ corr_vbl,
                                                const float* __restrict__ prior_mu,
                                                float* __restrict__ sums,
                                                float* __restrict__ s0a,
                                                float* __restrict__ s1a,
                                                float* __restrict__ s2a) {
    const int chunk = blockIdx.x;
    const int tid = threadIdx.x;  // 0..127
    const int d0 = tid * 4;
    const float t0m1 = (float)(chunk * ROWS) - 1.0f;

    float vv[4], cc[4], k0[4], L[4], S0[4], S1[4], S2[4], Dprev[4], invDprev[4];
#pragma unroll
    for (int j = 0; j < 4; ++j) {
        const int d = d0 + j;
        float spv = log1pf(expf(var_vbl[d]));
        float v = spv * spv;
        float c = v / (1.0f + expf(-corr_vbl[d]));
        vv[j] = v;
        cc[j] = c;
        k0[j] = (v - c) * prior_mu[d];      // (v-c)*mu0
        L[j] = 0.f; S0[j] = 0.f; S1[j] = 0.f; S2[j] = 0.f;
        Dprev[j] = fmaf(c, t0m1, v);        // D_{t0-1}
        invDprev[j] = __builtin_amdgcn_rcpf(Dprev[j]);
    }

    const float4* zp = reinterpret_cast<const float4*>(z)
                       + (size_t)chunk * ROWS * (DIM / 4) + tid;
    float tf = t0m1 + 1.0f;
#pragma unroll 4
    for (int r = 0; r < ROWS; ++r) {
        float4 zv = zp[(size_t)r * (DIM / 4)];
        float zz[4] = {zv.x, zv.y, zv.z, zv.w};
#pragma unroll
        for (int j = 0; j < 4; ++j) {
            float Dt = fmaf(cc[j], tf, vv[j]);             // v + c*t
            float invDt = __builtin_amdgcn_rcpf(Dt);
            float w = fmaf(Dprev[j], zz[j], -fmaf(cc[j], L[j], k0[j]));
            float rr = invDt * invDprev[j];
            S0[j] += rr;
            float rw = rr * w;
            S1[j] += rw;
            S2[j] = fmaf(rw, w, S2[j]);
            L[j] += zz[j];
            Dprev[j] = Dt;
            invDprev[j] = invDt;
        }
        tf += 1.0f;
    }

    const size_t o4 = (size_t)chunk * (DIM / 4) + tid;
    reinterpret_cast<float4*>(sums)[o4] = make_float4(L[0], L[1], L[2], L[3]);
    reinterpret_cast<float4*>(s0a)[o4] = make_float4(S0[0], S0[1], S0[2], S0[3]);
    reinterpret_cast<float4*>(s1a)[o4] = make_float4(S1[0], S1[1], S1[2], S1[3]);
    reinterpret_cast<float4*>(s2a)[o4] = make_float4(S2[0], S2[1], S2[2], S2[3]);
}

// K2a: group totals. grid=GROUPS, block=512.
__global__ __launch_bounds__(512) void k2a_gsum(const float* __restrict__ sums,
                                                float* __restrict__ gsums) {
    const int g = blockIdx.x;
    const int d = threadIdx.x;
    float vals[CPG];
#pragma unroll
    for (int i = 0; i < CPG; ++i)
        vals[i] = sums[(size_t)(g * CPG + i) * DIM + d];
    float run = 0.f;
#pragma unroll
    for (int i = 0; i < CPG; ++i) run += vals[i];
    gsums[(size_t)g * DIM + d] = run;
}

// K2b: exclusive scan over group totals (in place) + analytic log-det.
// Thread 0 STORES the logdet into out (initializes it; replaces memset).
__global__ __launch_bounds__(512) void k2b_scan(float* __restrict__ gsums,
                                                const float* __restrict__ var_vbl,
                                                const float* __restrict__ corr_vbl,
                                                float* __restrict__ out) {
    const int d = threadIdx.x;
    float vals[GROUPS];
#pragma unroll
    for (int g = 0; g < GROUPS; ++g)
        vals[g] = gsums[(size_t)g * DIM + d];
    float run = 0.f;
#pragma unroll
    for (int g = 0; g < GROUPS; ++g) {
        gsums[(size_t)g * DIM + d] = run;
        run += vals[g];
    }
    // Analytic: sum_t -0.5*log(2pi var_t) telescopes.
    double sp = log1p(exp((double)var_vbl[d]));
    double v = sp * sp;
    double cc = v / (1.0 + exp(-(double)corr_vbl[d]));
    double vmc = v - cc;
    double Dlast = v + cc * (double)(TT - 1);
    double Ld = -0.5 * ((double)TT * (log(TWO_PI) + log(vmc)) + log(Dlast / vmc));
    __shared__ double red[512];
    red[d] = Ld;
    __syncthreads();
    for (int s = 256; s > 0; s >>= 1) {
        if (d < s) red[d] += red[d + s];
        __syncthreads();
    }
    if (d == 0) out[0] = (float)red[0];
}

// K2c: combine moments with prefixes, reduce, atomicAdd. grid=GROUPS, block=512.
__global__ __launch_bounds__(512) void k2c_combine(const float* __restrict__ sums,
                                                   const float* __restrict__ gsums,
                                                   const float* __restrict__ s0a,
                                                   const float* __restrict__ s1a,
                                                   const float* __restrict__ s2a,
                                                   const float* __restrict__ var_vbl,
                                                   const float* __restrict__ corr_vbl,
                                                   float* __restrict__ out) {
    const int g = blockIdx.x;
    const int d = threadIdx.x;
    float spv = log1pf(expf(var_vbl[d]));
    float v = spv * spv;
    float c = v / (1.0f + expf(-corr_vbl[d]));
    float kq = 0.5f / (v - c);

    float run = gsums[(size_t)g * DIM + d];  // group-exclusive prefix
    float q = 0.f;
#pragma unroll
    for (int i = 0; i < CPG; ++i) {
        const size_t idx = (size_t)(g * CPG + i) * DIM + d;
        float s = sums[idx];
        float S0 = s0a[idx];
        float S1 = s1a[idx];
        float S2 = s2a[idx];
        float cP = c * run;
        q += kq * (S2 - 2.f * cP * S1 + cP * cP * S0);
        run += s;
    }

    // block reduce (8 waves) and subtract from out
    for (int off = 32; off > 0; off >>= 1) q += __shfl_down(q, off, 64);
    __shared__ float wsred[8];
    const int lane = d & 63, w = d >> 6;
    if (lane == 0) wsred[w] = q;
    __syncthreads();
    if (d == 0) {
        float tot = 0.f;
#pragma unroll
        for (int i = 0; i < 8; ++i) tot += wsred[i];
        atomicAdd(out, -tot);
    }
}

extern "C" void kernel_launch(void* const* d_in, const int* in_sizes, int n_in,
                              void* d_out, int out_size, void* d_ws, size_t ws_size,
                              hipStream_t stream) {
    const float* z = (const float*)d_in[0];
    const float* var_vbl = (const float*)d_in[1];
    const float* corr_vbl = (const float*)d_in[2];
    const float* prior_mu = (const float*)d_in[3];
    float* out = (float*)d_out;
    float* sums = (float*)d_ws;                          // CHUNKS*DIM (2 MB)
    float* s0a = sums + (size_t)CHUNKS * DIM;            // 2 MB
    float* s1a = s0a + (size_t)CHUNKS * DIM;             // 2 MB
    float* s2a = s1a + (size_t)CHUNKS * DIM;             // 2 MB
    float* gsums = s2a + (size_t)CHUNKS * DIM;           // GROUPS*DIM (128 KB)

    k1_fused<<<CHUNKS, 128, 0, stream>>>(z, var_vbl, corr_vbl, prior_mu,
                                         sums, s0a, s1a, s2a);
    k2a_gsum<<<GROUPS, 512, 0, stream>>>(sums, gsums);
    k2b_scan<<<1, 512, 0, stream>>>(gsums, var_vbl, corr_vbl, out);
    k2c_combine<<<GROUPS, 512, 0, stream>>>(sums, gsums, s0a, s1a, s2a,
                                            var_vbl, corr_vbl, out);
}